// Round 5
// baseline (9956.140 us; speedup 1.0000x reference)
//
#include <hip/hip_runtime.h>
#include <cmath>

namespace {
constexpr int B_ = 16, T_ = 512, P_ = 256, E_ = 128, NB_ = 4, K_ = 4;

__device__ __forceinline__ float rcpf(float x) { return __builtin_amdgcn_rcpf(x); }
__device__ __forceinline__ float fast_tanh(float x) {
    float a = fabsf(x);
    float t = __expf(-2.0f * a);
    float r = 1.0f - 2.0f * t * rcpf(1.0f + t);
    return copysignf(r, x);
}
// acc += s * w (paired; compiler can form v_pk_fma_f32)
__device__ __forceinline__ float2 pf(float s, float2 w, float2 a) {
    a.x = fmaf(s, w.x, a.x);
    a.y = fmaf(s, w.y, a.y);
    return a;
}
}

// ONE wave (64 lanes) per block, one block per batch element. Lane l owns the
// e-pair (2l, 2l+1) -> the full E=128 state is wave-local: ZERO barriers.
// The per-wave in-order LDS pipe makes write->read (s broadcast) and
// scatter(t) -> gather(t+1) safe by program order alone. W_p column pair in
// VGPRs (256); matvec via wave-uniform ds_read_b128 broadcast of s.
__global__ __launch_bounds__(64, 1)
void swarm_ring_kernel(const float* __restrict__ x,            // (B,T,8)
                       const float* __restrict__ W_in,         // (8,E)
                       const float* __restrict__ b_in,         // (E)
                       const float* __restrict__ W_out,        // (E,8)
                       const float* __restrict__ b_out,        // (8)
                       const float* __restrict__ W_p,          // (E,E)
                       const float* __restrict__ b_p,          // (E)
                       const float* __restrict__ ptr_dest,     // (NB,P)
                       const float* __restrict__ jump_W,       // (NB,E)
                       const float* __restrict__ jump_b,       // (NB)
                       const float* __restrict__ ctx_strength, // (NB)
                       const float* __restrict__ phase_bias,   // (NB,E)
                       const float* __restrict__ pointer_init, // (NB,B)
                       float* __restrict__ out)                // (B,T,8)
{
    __shared__ alignas(16) float ring[P_ * E_];   // 128 KiB
    __shared__ alignas(16) float s_mem[E_];

    const int tid = threadIdx.x;                  // 0..63
    const int b   = blockIdx.x;
    const int e0  = tid << 1;                     // lane's e-pair: e0, e0+1

    for (int k4 = tid; k4 < P_ * E_ / 4; k4 += 64)
        ((float4*)ring)[k4] = make_float4(0.f, 0.f, 0.f, 0.f);

    float2 wp2[128];                              // W_p[k][e0..e0+1]
    #pragma unroll
    for (int k = 0; k < 128; ++k)
        wp2[k] = *(const float2*)(W_p + k * E_ + e0);

    const float2 bin2 = *(const float2*)(b_in + e0);
    const float2 bp2  = *(const float2*)(b_p + e0);

    float2 pb2[NB_], jw2[NB_], hid2[NB_];
    float  sigc[NB_], jb_r[NB_], ptrv[NB_];
    #pragma unroll
    for (int i = 0; i < NB_; ++i) {
        float2 pb = *(const float2*)(phase_bias + i * E_ + e0);
        pb2[i] = make_float2(0.1f * pb.x, 0.1f * pb.y);
        jw2[i] = *(const float2*)(jump_W + i * E_ + e0);
        sigc[i] = 1.0f / (1.0f + __expf(-ctx_strength[i]));
        jb_r[i] = jump_b[i];
        hid2[i] = make_float2(0.f, 0.f);
        ptrv[i] = pointer_init[i * B_ + b];
    }
    float bo[8];
    #pragma unroll
    for (int m = 0; m < 8; ++m) bo[m] = b_out[m];

    const float* xb = x + (size_t)b * T_ * 8;
    float xt[8];
    {
        float4 a0 = ((const float4*)xb)[0], a1 = ((const float4*)xb)[1];
        xt[0]=a0.x; xt[1]=a0.y; xt[2]=a0.z; xt[3]=a0.w;
        xt[4]=a1.x; xt[5]=a1.y; xt[6]=a1.z; xt[7]=a1.w;
    }

    const float Cw1 = 0.8824969f, Cw2 = 0.60653066f, Cw3 = 0.32465247f, Cw4 = 0.13533528f;
    const float Dw1 = 0.7788008f, Dw2 = 0.36787944f, Dw3 = 0.105399225f, Dw4 = 0.018315639f;

    for (int t = 0; t < T_; ++t) {
        // ---- geometry, softmax weights, jump-target prefetch (R2-proven math)
        int   baseA[NB_];
        float fA[NB_], psinv[NB_], jt[NB_], wgt[NB_][9];
        #pragma unroll
        for (int i = 0; i < NB_; ++i) {
            const float p = ptrv[i];
            const int base = (int)p;
            baseA[i] = base;
            jt[i] = ptr_dest[i * P_ + base];
            const float f = p - (float)base;
            fA[i] = f;
            const float r  = __expf(0.25f * f);
            const float r2 = r * r, r3 = r2 * r, r4 = r2 * r2;
            const float ri = rcpf(r), ri2 = ri * ri, ri3 = ri2 * ri, ri4 = ri2 * ri2;
            const float p0 = Cw4*ri4, p1 = Cw3*ri3, p2 = Cw2*ri2, p3 = Cw1*ri, p4 = 1.0f,
                        p5 = Cw1*r,  p6 = Cw2*r2,  p7 = Cw3*r3,  p8 = Cw4*r4;
            const float sum = ((p0+p1)+(p2+p3)) + ((p4+p5)+(p6+p7)) + p8;
            const float inv = rcpf(sum);
            psinv[i] = inv;
            wgt[i][0]=p0*inv; wgt[i][1]=p1*inv; wgt[i][2]=p2*inv; wgt[i][3]=p3*inv;
            wgt[i][4]=p4*inv; wgt[i][5]=p5*inv; wgt[i][6]=p6*inv; wgt[i][7]=p7*inv;
            wgt[i][8]=p8*inv;
        }

        // ---- inp = x_t @ W_in + b_in (W_in reloaded per step, L1-hot)
        float2 inp2 = bin2;
        #pragma unroll
        for (int k = 0; k < 8; ++k) {
            const float2 wk = *(const float2*)(W_in + k * E_ + e0);
            inp2 = pf(xt[k], wk, inp2);
        }

        // ---- all 4 bots' gathers from step-start ring (loads first, then math)
        float2 g[NB_][9];
        #pragma unroll
        for (int i = 0; i < NB_; ++i)
            #pragma unroll
            for (int o = 0; o < 9; ++o) {
                const int row = (baseA[i] + o - K_) & (P_ - 1);
                g[i][o] = *(const float2*)(ring + row * E_ + e0);
            }
        float2 ctxp[NB_];
        #pragma unroll
        for (int i = 0; i < NB_; ++i) {
            float2 c = make_float2(0.f, 0.f);
            #pragma unroll
            for (int o = 0; o < 9; ++o) c = pf(wgt[i][o], g[i][o], c);
            ctxp[i] = c;
        }

        // ---- cross-bot correction coefficients (pointers only; R2-proven)
        float coefm[NB_][NB_];
        #pragma unroll
        for (int j = 1; j < NB_; ++j) {
            #pragma unroll
            for (int i = 0; i < j; ++i) {
                const int dd = ((baseA[j] - baseA[i] + 128) & 255) - 128;
                float c = 0.f;
                if (dd >= -8 && dd <= 8) {
                    const float A = (float)dd - fA[i];
                    const float s  = __expf(-0.25f * (A - fA[j]));
                    const float G  = __expf(0.125f * (fA[i] * fA[i] - A * A));
                    const float s2p = s * s, s3p = s2p * s, s4p = s2p * s2p;
                    const float si = rcpf(s), si2 = si * si, si3 = si2 * si, si4 = si2 * si2;
                    float acc = 0.f;
                    acc += (dd >= 0)              ? Dw4 * si4 : 0.f;
                    acc += (dd >= -1 && dd <= 7)  ? Dw3 * si3 : 0.f;
                    acc += (dd >= -2 && dd <= 6)  ? Dw2 * si2 : 0.f;
                    acc += (dd >= -3 && dd <= 5)  ? Dw1 * si  : 0.f;
                    acc += (dd >= -4 && dd <= 4)  ? 1.0f      : 0.f;
                    acc += (dd >= -5 && dd <= 3)  ? Dw1 * s   : 0.f;
                    acc += (dd >= -6 && dd <= 2)  ? Dw2 * s2p : 0.f;
                    acc += (dd >= -7 && dd <= 1)  ? Dw3 * s3p : 0.f;
                    acc += (dd <= 0)              ? Dw4 * s4p : 0.f;
                    c = psinv[i] * psinv[j] * G * acc;
                }
                coefm[j][i] = c;
            }
        }

        // prefetch next x_t
        float xtn[8];
        if (t + 1 < T_) {
            float4 a0 = ((const float4*)(xb + (t + 1) * 8))[0];
            float4 a1 = ((const float4*)(xb + (t + 1) * 8))[1];
            xtn[0]=a0.x; xtn[1]=a0.y; xtn[2]=a0.z; xtn[3]=a0.w;
            xtn[4]=a1.x; xtn[5]=a1.y; xtn[6]=a1.z; xtn[7]=a1.w;
        } else {
            #pragma unroll
            for (int k = 0; k < 8; ++k) xtn[k] = 0.f;
        }

        // ---- serial bot chain, BARRIER-FREE (single wave, in-order DS pipe)
        float2 sv2[NB_];
        #pragma unroll
        for (int j = 0; j < NB_; ++j) {
            float2 ctx = ctxp[j];
            #pragma unroll
            for (int i = 0; i < j; ++i) ctx = pf(coefm[j][i], sv2[i], ctx);

            float2 s1;
            s1.x = fast_tanh(fmaf(sigc[j], ctx.x, inp2.x + pb2[j].x + hid2[j].x));
            s1.y = fast_tanh(fmaf(sigc[j], ctx.y, inp2.y + pb2[j].y + hid2[j].y));
            *(float2*)(s_mem + e0) = s1;          // lane-owned pair; in-order RAW

            // matvec: wave-uniform b128 broadcast reads of s, 4 paired accums
            float2 a0 = make_float2(0.f, 0.f), a1 = a0, a2 = a0, a3 = a0;
            const float4* sm = (const float4*)s_mem;
            #pragma unroll
            for (int kb = 0; kb < 32; ++kb) {
                const float4 s4 = sm[kb];
                a0 = pf(s4.x, wp2[4 * kb + 0], a0);
                a1 = pf(s4.y, wp2[4 * kb + 1], a1);
                a2 = pf(s4.z, wp2[4 * kb + 2], a2);
                a3 = pf(s4.w, wp2[4 * kb + 3], a3);
            }
            float2 s2;
            s2.x = fast_tanh(((a0.x + a1.x) + (a2.x + a3.x)) + bp2.x);
            s2.y = fast_tanh(((a0.y + a1.y) + (a2.y + a3.y)) + bp2.y);
            sv2[j] = s2; hid2[j] = s2;

            // scatter: sole owner of (row, e-pair); reads batched before writes
            float2 rv[9];
            #pragma unroll
            for (int o = 0; o < 9; ++o) {
                const int row = (baseA[j] + o - K_) & (P_ - 1);
                rv[o] = *(const float2*)(ring + row * E_ + e0);
            }
            #pragma unroll
            for (int o = 0; o < 9; ++o) {
                const int row = (baseA[j] + o - K_) & (P_ - 1);
                float2 nv;
                nv.x = fmaf(wgt[j][o], s2.x, rv[o].x);
                nv.y = fmaf(wgt[j][o], s2.y, rv[o].y);
                *(float2*)(ring + row * E_ + e0) = nv;
            }
        }

        // ---- reductions fully in-wave: 8 out dots + 4 jump dots
        float v[12];
        {
            const float2 ssum2 = make_float2(
                (sv2[0].x + sv2[1].x) + (sv2[2].x + sv2[3].x),
                (sv2[0].y + sv2[1].y) + (sv2[2].y + sv2[3].y));
            const float4 woA0 = *(const float4*)(W_out + e0 * 8);
            const float4 woA1 = *(const float4*)(W_out + e0 * 8 + 4);
            const float4 woB0 = *(const float4*)(W_out + (e0 + 1) * 8);
            const float4 woB1 = *(const float4*)(W_out + (e0 + 1) * 8 + 4);
            v[0] = fmaf(ssum2.y, woB0.x, ssum2.x * woA0.x);
            v[1] = fmaf(ssum2.y, woB0.y, ssum2.x * woA0.y);
            v[2] = fmaf(ssum2.y, woB0.z, ssum2.x * woA0.z);
            v[3] = fmaf(ssum2.y, woB0.w, ssum2.x * woA0.w);
            v[4] = fmaf(ssum2.y, woB1.x, ssum2.x * woA1.x);
            v[5] = fmaf(ssum2.y, woB1.y, ssum2.x * woA1.y);
            v[6] = fmaf(ssum2.y, woB1.z, ssum2.x * woA1.z);
            v[7] = fmaf(ssum2.y, woB1.w, ssum2.x * woA1.w);
            #pragma unroll
            for (int i = 0; i < NB_; ++i)
                v[8 + i] = fmaf(sv2[i].y, jw2[i].y, sv2[i].x * jw2[i].x);
            #pragma unroll
            for (int m = 0; m < 12; ++m) {
                float vv = v[m];
                vv += __shfl_xor(vv, 1);
                vv += __shfl_xor(vv, 2);
                vv += __shfl_xor(vv, 4);
                vv += __shfl_xor(vv, 8);
                vv += __shfl_xor(vv, 16);
                vv += __shfl_xor(vv, 32);
                v[m] = vv;
            }
        }

        // pointer updates (uniform across lanes, deterministic)
        #pragma unroll
        for (int i = 0; i < NB_; ++i) {
            const float z = v[8 + i] + jb_r[i];
            float np;
            if (z > 0.0f) np = jt[i];
            else { np = ptrv[i] + 1.0f; if (np >= 256.0f) np -= 256.0f; }
            ptrv[i] = np;
        }
        if (tid == 0) {
            float4 o0 = make_float4(fmaf(0.25f, v[0], bo[0]), fmaf(0.25f, v[1], bo[1]),
                                    fmaf(0.25f, v[2], bo[2]), fmaf(0.25f, v[3], bo[3]));
            float4 o1 = make_float4(fmaf(0.25f, v[4], bo[4]), fmaf(0.25f, v[5], bo[5]),
                                    fmaf(0.25f, v[6], bo[6]), fmaf(0.25f, v[7], bo[7]));
            float4* op = (float4*)(out + ((size_t)b * T_ + t) * 8);
            op[0] = o0;
            op[1] = o1;
        }

        #pragma unroll
        for (int k = 0; k < 8; ++k) xt[k] = xtn[k];
    }
}

extern "C" void kernel_launch(void* const* d_in, const int* in_sizes, int n_in,
                              void* d_out, int out_size, void* d_ws, size_t ws_size,
                              hipStream_t stream) {
    (void)in_sizes; (void)n_in; (void)out_size; (void)d_ws; (void)ws_size;
    swarm_ring_kernel<<<dim3(B_), dim3(64), 0, stream>>>(
        (const float*)d_in[0],  (const float*)d_in[1],  (const float*)d_in[2],
        (const float*)d_in[3],  (const float*)d_in[4],  (const float*)d_in[5],
        (const float*)d_in[6],  (const float*)d_in[7],  (const float*)d_in[8],
        (const float*)d_in[9],  (const float*)d_in[10], (const float*)d_in[11],
        (const float*)d_in[12], (float*)d_out);
}

// Round 6
// 4631.134 us; speedup vs baseline: 2.1498x; 2.1498x over previous
//
#include <hip/hip_runtime.h>
#include <cmath>

namespace {
constexpr int B_ = 16, T_ = 512, P_ = 256, E_ = 128, NB_ = 4, K_ = 4;

__device__ __forceinline__ float rcpf(float x) { return __builtin_amdgcn_rcpf(x); }
__device__ __forceinline__ float fast_tanh(float x) {
    float a = fabsf(x);
    float t = __expf(-2.0f * a);
    float r = 1.0f - 2.0f * t * rcpf(1.0f + t);
    return copysignf(r, x);
}
// barrier ordering LDS only (no vmcnt drain)
__device__ __forceinline__ void bar_lds() {
    asm volatile("s_waitcnt lgkmcnt(0)\n\ts_barrier" ::: "memory");
}
__device__ __forceinline__ float2 pf(float s, float2 w, float2 a) {
    a.x = fmaf(s, w.x, a.x);
    a.y = fmaf(s, w.y, a.y);
    return a;
}
}

// 4 waves / 256 threads, 1 block per batch. ring (128 KiB) in LDS.
// e-ownership (gather/scatter/s1/s2): e = 32*wave + (lane&31), khalf = lane>>5
// duplicates. Matvec is OWN-K: wave w uses only s1[k], k in [32w,32w+32) --
// values its own lanes computed (LDS write->read same wave is in-order, no
// barrier) -- and accumulates partials for e-pair (2*lane, 2*lane+1) with a
// 64-VGPR W_p slice. Cross-wave combine: 1 ds_write_b64 + barrier + 4
// ds_read_b32 (conflict-free layouts). 5 barriers/step, short drains.
__global__ __launch_bounds__(256, 1)
void swarm_ring_kernel(const float* __restrict__ x,            // (B,T,8)
                       const float* __restrict__ W_in,         // (8,E)
                       const float* __restrict__ b_in,         // (E)
                       const float* __restrict__ W_out,        // (E,8)
                       const float* __restrict__ b_out,        // (8)
                       const float* __restrict__ W_p,          // (E,E)
                       const float* __restrict__ b_p,          // (E)
                       const float* __restrict__ ptr_dest,     // (NB,P)
                       const float* __restrict__ jump_W,       // (NB,E)
                       const float* __restrict__ jump_b,       // (NB)
                       const float* __restrict__ ctx_strength, // (NB)
                       const float* __restrict__ phase_bias,   // (NB,E)
                       const float* __restrict__ pointer_init, // (NB,B)
                       float* __restrict__ out)                // (B,T,8)
{
    __shared__ alignas(16) float ring[P_ * E_];   // 128 KiB
    __shared__ alignas(16) float s_own[4][32];    // wave-private s1 slices
    __shared__ alignas(16) float part[2][4][E_];  // [buf][wave][e] partials
    __shared__ alignas(16) float red[16];         // jump dots
    __shared__ alignas(16) float redo[32];        // out dots

    const int tid   = threadIdx.x;
    const int b     = blockIdx.x;
    const int wave  = tid >> 6;
    const int lane  = tid & 63;
    const int khalf = lane >> 5;
    const int e     = (wave << 5) | (lane & 31);  // owned e
    const int me    = lane << 1;                  // matvec e-pair: me, me+1

    for (int k4 = tid; k4 < P_ * E_ / 4; k4 += 256)
        ((float4*)ring)[k4] = make_float4(0.f, 0.f, 0.f, 0.f);

    float2 wp2[32];                               // W_p[32*wave+kk][me..me+1]
    #pragma unroll
    for (int kk = 0; kk < 32; ++kk)
        wp2[kk] = *(const float2*)(W_p + (32 * wave + kk) * E_ + me);

    const float bin_r = b_in[e];
    const float bp_r  = b_p[e];
    float win_r[8];
    #pragma unroll
    for (int k = 0; k < 8; ++k) win_r[k] = W_in[k * E_ + e];
    float wsel[4];                                // W_out[e][khalf*4+u]
    #pragma unroll
    for (int u = 0; u < 4; ++u) wsel[u] = W_out[e * 8 + khalf * 4 + u];

    float pb_r[NB_], jw_r[NB_], sigc[NB_], jb_r[NB_], hid[NB_], ptrv[NB_];
    #pragma unroll
    for (int i = 0; i < NB_; ++i) {
        pb_r[i] = 0.1f * phase_bias[i * E_ + e];
        jw_r[i] = jump_W[i * E_ + e];
        sigc[i] = 1.0f / (1.0f + __expf(-ctx_strength[i]));
        jb_r[i] = jump_b[i];
        hid[i]  = 0.0f;
        ptrv[i] = pointer_init[i * B_ + b];
    }
    const float bout_r = (tid < 8) ? b_out[tid] : 0.0f;

    const float* xb = x + (size_t)b * T_ * 8;
    float xt[8];
    {
        float4 a0 = ((const float4*)xb)[0], a1 = ((const float4*)xb)[1];
        xt[0]=a0.x; xt[1]=a0.y; xt[2]=a0.z; xt[3]=a0.w;
        xt[4]=a1.x; xt[5]=a1.y; xt[6]=a1.z; xt[7]=a1.w;
    }

    const float Cw1 = 0.8824969f, Cw2 = 0.60653066f, Cw3 = 0.32465247f, Cw4 = 0.13533528f;
    const float Dw1 = 0.7788008f, Dw2 = 0.36787944f, Dw3 = 0.105399225f, Dw4 = 0.018315639f;

    bar_lds();

    for (int t = 0; t < T_; ++t) {
        // ---- geometry, softmax weights, jump-target prefetch (R2/R4-proven)
        int   baseA[NB_];
        float fA[NB_], psinv[NB_], jt[NB_], wgt[NB_][9];
        #pragma unroll
        for (int i = 0; i < NB_; ++i) {
            const float p = ptrv[i];
            const int base = (int)p;
            baseA[i] = base;
            jt[i] = ptr_dest[i * P_ + base];
            const float f = p - (float)base;
            fA[i] = f;
            const float r  = __expf(0.25f * f);
            const float r2 = r * r, r3 = r2 * r, r4 = r2 * r2;
            const float ri = rcpf(r), ri2 = ri * ri, ri3 = ri2 * ri, ri4 = ri2 * ri2;
            const float p0 = Cw4*ri4, p1 = Cw3*ri3, p2 = Cw2*ri2, p3 = Cw1*ri, p4 = 1.0f,
                        p5 = Cw1*r,  p6 = Cw2*r2,  p7 = Cw3*r3,  p8 = Cw4*r4;
            const float sum = ((p0+p1)+(p2+p3)) + ((p4+p5)+(p6+p7)) + p8;
            const float inv = rcpf(sum);
            psinv[i] = inv;
            wgt[i][0]=p0*inv; wgt[i][1]=p1*inv; wgt[i][2]=p2*inv; wgt[i][3]=p3*inv;
            wgt[i][4]=p4*inv; wgt[i][5]=p5*inv; wgt[i][6]=p6*inv; wgt[i][7]=p7*inv;
            wgt[i][8]=p8*inv;
        }

        // ---- gathers (khalf-split offsets, cndmask weights) + ctx partials
        float ctxp[NB_];
        #pragma unroll
        for (int i = 0; i < NB_; ++i) {
            float c = 0.f;
            #pragma unroll
            for (int u = 0; u < 5; ++u) {
                const float wlo = wgt[i][u];
                const float whi = (u == 0) ? 0.f : wgt[i][u + 4];
                const float wv  = khalf ? whi : wlo;
                const int row = (baseA[i] + u + (khalf << 2) - K_) & (P_ - 1);
                c = fmaf(wv, ring[row * E_ + e], c);
            }
            c += __shfl_xor(c, 32);
            ctxp[i] = c;
        }

        // ---- cross-bot correction coefficients (pointers only)
        float coefm[NB_][NB_];
        #pragma unroll
        for (int j = 1; j < NB_; ++j) {
            #pragma unroll
            for (int i = 0; i < j; ++i) {
                const int dd = ((baseA[j] - baseA[i] + 128) & 255) - 128;
                float c = 0.f;
                if (dd >= -8 && dd <= 8) {
                    const float A = (float)dd - fA[i];
                    const float s  = __expf(-0.25f * (A - fA[j]));
                    const float G  = __expf(0.125f * (fA[i] * fA[i] - A * A));
                    const float s2p = s * s, s3p = s2p * s, s4p = s2p * s2p;
                    const float si = rcpf(s), si2 = si * si, si3 = si2 * si, si4 = si2 * si2;
                    float acc = 0.f;
                    acc += (dd >= 0)              ? Dw4 * si4 : 0.f;
                    acc += (dd >= -1 && dd <= 7)  ? Dw3 * si3 : 0.f;
                    acc += (dd >= -2 && dd <= 6)  ? Dw2 * si2 : 0.f;
                    acc += (dd >= -3 && dd <= 5)  ? Dw1 * si  : 0.f;
                    acc += (dd >= -4 && dd <= 4)  ? 1.0f      : 0.f;
                    acc += (dd >= -5 && dd <= 3)  ? Dw1 * s   : 0.f;
                    acc += (dd >= -6 && dd <= 2)  ? Dw2 * s2p : 0.f;
                    acc += (dd >= -7 && dd <= 1)  ? Dw3 * s3p : 0.f;
                    acc += (dd <= 0)              ? Dw4 * s4p : 0.f;
                    c = psinv[i] * psinv[j] * G * acc;
                }
                coefm[j][i] = c;
            }
        }

        float inp = bin_r;
        #pragma unroll
        for (int k = 0; k < 8; ++k) inp = fmaf(xt[k], win_r[k], inp);

        float xtn[8];
        if (t + 1 < T_) {
            float4 a0 = ((const float4*)(xb + (t + 1) * 8))[0];
            float4 a1 = ((const float4*)(xb + (t + 1) * 8))[1];
            xtn[0]=a0.x; xtn[1]=a0.y; xtn[2]=a0.z; xtn[3]=a0.w;
            xtn[4]=a1.x; xtn[5]=a1.y; xtn[6]=a1.z; xtn[7]=a1.w;
        } else {
            #pragma unroll
            for (int k = 0; k < 8; ++k) xtn[k] = 0.f;
        }

        // ---- serial bot chain: own-k matvec, 1 barrier per bot
        float sv[NB_];
        #pragma unroll
        for (int j = 0; j < NB_; ++j) {
            float ctx = ctxp[j];
            #pragma unroll
            for (int i = 0; i < j; ++i) ctx = fmaf(coefm[j][i], sv[i], ctx);
            const float s1 = fast_tanh(fmaf(sigc[j], ctx, inp + pb_r[j] + hid[j]));
            if (lane < 32) s_own[wave][lane] = s1;    // wave-private; in-order RAW

            // own-k partials for e-pair (me, me+1): 8 b128 broadcasts + 32 pf
            float2 a0 = make_float2(0.f, 0.f), a1 = a0;
            const float4* sm = (const float4*)s_own[wave];
            #pragma unroll
            for (int kb = 0; kb < 8; ++kb) {
                const float4 s4 = sm[kb];
                a0 = pf(s4.x, wp2[4 * kb + 0], a0);
                a1 = pf(s4.y, wp2[4 * kb + 1], a1);
                a0 = pf(s4.z, wp2[4 * kb + 2], a0);
                a1 = pf(s4.w, wp2[4 * kb + 3], a1);
            }
            const float2 acc = make_float2(a0.x + a1.x, a0.y + a1.y);
            *(float2*)(&part[j & 1][wave][me]) = acc;  // ds_write_b64
            bar_lds();                                 // all 4 waves' partials

            const float ps = (part[j & 1][0][e] + part[j & 1][1][e]) +
                             (part[j & 1][2][e] + part[j & 1][3][e]);
            const float s2 = fast_tanh(ps + bp_r);
            sv[j] = s2; hid[j] = s2;

            // parity-owned scatter (deterministic): khalf owns rows == khalf (mod 2)
            const int o0 = (baseA[j] ^ khalf) & 1;
            #pragma unroll
            for (int u = 0; u < 4; ++u) {
                const float wa = wgt[j][2 * u];
                const float wb = wgt[j][2 * u + 1];
                const float wv = o0 ? wb : wa;
                const int row = (baseA[j] + 2 * u + o0 - K_) & (P_ - 1);
                atomicAdd(&ring[row * E_ + e], wv * s2);
            }
            if (o0 == 0) {
                const int row = (baseA[j] + 8 - K_) & (P_ - 1);
                atomicAdd(&ring[row * E_ + e], wgt[j][8] * s2);
            }
        }

        // ---- jump dots (khalf0: bots 0,1; khalf1: bots 2,3)
        {
            float va = khalf ? sv[2] * jw_r[2] : sv[0] * jw_r[0];
            float vb = khalf ? sv[3] * jw_r[3] : sv[1] * jw_r[1];
            #pragma unroll
            for (int off = 1; off < 32; off <<= 1) {
                va += __shfl_xor(va, off);
                vb += __shfl_xor(vb, off);
            }
            if ((lane & 31) == 0)
                ((float2*)red)[wave * 2 + khalf] = make_float2(va, vb);
        }

        // ---- out dots (khalf0: dims 0-3; khalf1: dims 4-7)
        {
            const float ssum = (sv[0] + sv[1]) + (sv[2] + sv[3]);
            float u0 = ssum * wsel[0], u1 = ssum * wsel[1],
                  u2 = ssum * wsel[2], u3 = ssum * wsel[3];
            #pragma unroll
            for (int off = 1; off < 32; off <<= 1) {
                u0 += __shfl_xor(u0, off); u1 += __shfl_xor(u1, off);
                u2 += __shfl_xor(u2, off); u3 += __shfl_xor(u3, off);
            }
            if ((lane & 31) == 0)
                ((float4*)redo)[wave * 2 + khalf] = make_float4(u0, u1, u2, u3);
        }

        bar_lds();                                    // scatters + red/redo visible

        {
            const float4 r0 = ((const float4*)red)[0];
            const float4 r1 = ((const float4*)red)[1];
            const float4 r2 = ((const float4*)red)[2];
            const float4 r3 = ((const float4*)red)[3];
            const float zz[4] = {
                ((r0.x + r1.x) + (r2.x + r3.x)) + jb_r[0],
                ((r0.y + r1.y) + (r2.y + r3.y)) + jb_r[1],
                ((r0.z + r1.z) + (r2.z + r3.z)) + jb_r[2],
                ((r0.w + r1.w) + (r2.w + r3.w)) + jb_r[3]};
            #pragma unroll
            for (int i = 0; i < NB_; ++i) {
                float np;
                if (zz[i] > 0.0f) np = jt[i];
                else { np = ptrv[i] + 1.0f; if (np >= 256.0f) np -= 256.0f; }
                ptrv[i] = np;
            }
        }
        if (tid < 8) {
            const float ov = 0.25f * ((redo[tid] + redo[8 + tid]) +
                                      (redo[16 + tid] + redo[24 + tid])) + bout_r;
            out[((size_t)b * T_ + t) * 8 + tid] = ov;
        }

        #pragma unroll
        for (int k = 0; k < 8; ++k) xt[k] = xtn[k];
    }
}

extern "C" void kernel_launch(void* const* d_in, const int* in_sizes, int n_in,
                              void* d_out, int out_size, void* d_ws, size_t ws_size,
                              hipStream_t stream) {
    (void)in_sizes; (void)n_in; (void)out_size; (void)d_ws; (void)ws_size;
    swarm_ring_kernel<<<dim3(B_), dim3(256), 0, stream>>>(
        (const float*)d_in[0],  (const float*)d_in[1],  (const float*)d_in[2],
        (const float*)d_in[3],  (const float*)d_in[4],  (const float*)d_in[5],
        (const float*)d_in[6],  (const float*)d_in[7],  (const float*)d_in[8],
        (const float*)d_in[9],  (const float*)d_in[10], (const float*)d_in[11],
        (const float*)d_in[12], (float*)d_out);
}

// Round 7
// 2175.059 us; speedup vs baseline: 4.5774x; 2.1292x over previous
//
#include <hip/hip_runtime.h>
#include <cmath>

namespace {
constexpr int B_ = 16, T_ = 512, P_ = 256, E_ = 128, NB_ = 4, K_ = 4;

__device__ __forceinline__ float rcpf(float x) { return __builtin_amdgcn_rcpf(x); }
__device__ __forceinline__ float fast_tanh(float x) {
    float a = fabsf(x);
    float t = __expf(-2.0f * a);
    float r = 1.0f - 2.0f * t * rcpf(1.0f + t);
    return copysignf(r, x);
}
}

// R2-proven skeleton: 4 waves / 256 threads, 1 block per batch, ring in LDS,
// e = 32*wave + (lane&31), khalf = lane>>5 (k-split of W_p matvec, combined
// via shfl_xor(32)). Plain __syncthreads, plain parity-owned += scatter.
// NEW: block-uniform independence test. When all 6 bot pairs have |dd|>8,
// windows are disjoint -> bots exactly independent -> batch all 4 s1's, ONE
// barrier, s4[k] float4 read gives all 4 bots per ds_read_b128 (4 indep FMA
// chains), 4 s2's, 4 disjoint scatters. Arithmetic bit-identical to serial.
__global__ __launch_bounds__(256, 1)
void swarm_ring_kernel(const float* __restrict__ x,            // (B,T,8)
                       const float* __restrict__ W_in,         // (8,E)
                       const float* __restrict__ b_in,         // (E)
                       const float* __restrict__ W_out,        // (E,8)
                       const float* __restrict__ b_out,        // (8)
                       const float* __restrict__ W_p,          // (E,E)
                       const float* __restrict__ b_p,          // (E)
                       const float* __restrict__ ptr_dest,     // (NB,P)
                       const float* __restrict__ jump_W,       // (NB,E)
                       const float* __restrict__ jump_b,       // (NB)
                       const float* __restrict__ ctx_strength, // (NB)
                       const float* __restrict__ phase_bias,   // (NB,E)
                       const float* __restrict__ pointer_init, // (NB,B)
                       float* __restrict__ out)                // (B,T,8)
{
    __shared__ alignas(16) float  ring[P_ * E_];  // 128 KiB
    __shared__ alignas(16) float  s_buf[2 * E_];  // slow path s broadcast
    __shared__ alignas(16) float4 s4[E_];         // fast path: s4[k] = s1 of bots 0..3
    __shared__ alignas(16) float  red[16];        // jump dots
    __shared__ alignas(16) float  redo[32];       // out dots

    const int tid   = threadIdx.x;
    const int b     = blockIdx.x;
    const int wave  = tid >> 6;
    const int lane  = tid & 63;
    const int khalf = lane >> 5;
    const int e     = (wave << 5) | (lane & 31);

    for (int k4 = tid; k4 < P_ * E_ / 4; k4 += 256)
        ((float4*)ring)[k4] = make_float4(0.f, 0.f, 0.f, 0.f);

    float wp[64];                                 // W_p[khalf*64+kk][e]
    #pragma unroll
    for (int kk = 0; kk < 64; ++kk)
        wp[kk] = W_p[(khalf * 64 + kk) * E_ + e];

    const float bin_r = b_in[e];
    const float bp_r  = b_p[e];
    float win_r[8];
    #pragma unroll
    for (int k = 0; k < 8; ++k) win_r[k] = W_in[k * E_ + e];
    float wsel[4];                                // W_out[e][khalf*4+u]
    #pragma unroll
    for (int u = 0; u < 4; ++u) wsel[u] = W_out[e * 8 + khalf * 4 + u];

    float pb_r[NB_], jw_r[NB_], sigc[NB_], jb_r[NB_], hid[NB_], ptrv[NB_];
    #pragma unroll
    for (int i = 0; i < NB_; ++i) {
        pb_r[i] = 0.1f * phase_bias[i * E_ + e];
        jw_r[i] = jump_W[i * E_ + e];
        sigc[i] = 1.0f / (1.0f + __expf(-ctx_strength[i]));
        jb_r[i] = jump_b[i];
        hid[i]  = 0.0f;
        ptrv[i] = pointer_init[i * B_ + b];
    }
    const float bout_r = (tid < 8) ? b_out[tid] : 0.0f;

    const float* xb = x + (size_t)b * T_ * 8;
    float xt[8];
    {
        float4 a0 = ((const float4*)xb)[0], a1 = ((const float4*)xb)[1];
        xt[0]=a0.x; xt[1]=a0.y; xt[2]=a0.z; xt[3]=a0.w;
        xt[4]=a1.x; xt[5]=a1.y; xt[6]=a1.z; xt[7]=a1.w;
    }

    const float Cw1 = 0.8824969f, Cw2 = 0.60653066f, Cw3 = 0.32465247f, Cw4 = 0.13533528f;
    const float Dw1 = 0.7788008f, Dw2 = 0.36787944f, Dw3 = 0.105399225f, Dw4 = 0.018315639f;

    __syncthreads();

    for (int t = 0; t < T_; ++t) {
        // ---- geometry, softmax weights, jump-target prefetch (R2-proven)
        int   baseA[NB_];
        float fA[NB_], psinv[NB_], jt[NB_], wgt[NB_][9];
        #pragma unroll
        for (int i = 0; i < NB_; ++i) {
            const float p = ptrv[i];
            const int base = (int)p;
            baseA[i] = base;
            jt[i] = ptr_dest[i * P_ + base];
            const float f = p - (float)base;
            fA[i] = f;
            const float r  = __expf(0.25f * f);
            const float r2 = r * r, r3 = r2 * r, r4 = r2 * r2;
            const float ri = rcpf(r), ri2 = ri * ri, ri3 = ri2 * ri, ri4 = ri2 * ri2;
            const float p0 = Cw4*ri4, p1 = Cw3*ri3, p2 = Cw2*ri2, p3 = Cw1*ri, p4 = 1.0f,
                        p5 = Cw1*r,  p6 = Cw2*r2,  p7 = Cw3*r3,  p8 = Cw4*r4;
            const float sum = ((p0+p1)+(p2+p3)) + ((p4+p5)+(p6+p7)) + p8;
            const float inv = rcpf(sum);
            psinv[i] = inv;
            wgt[i][0]=p0*inv; wgt[i][1]=p1*inv; wgt[i][2]=p2*inv; wgt[i][3]=p3*inv;
            wgt[i][4]=p4*inv; wgt[i][5]=p5*inv; wgt[i][6]=p6*inv; wgt[i][7]=p7*inv;
            wgt[i][8]=p8*inv;
        }

        // ---- block-uniform independence test (pointers only)
        int ddm[NB_][NB_];
        bool overlap = false;
        #pragma unroll
        for (int j = 1; j < NB_; ++j)
            #pragma unroll
            for (int i = 0; i < j; ++i) {
                const int dd = ((baseA[j] - baseA[i] + 128) & 255) - 128;
                ddm[j][i] = dd;
                overlap = overlap || (dd >= -8 && dd <= 8);
            }

        // ---- gathers (khalf-split offsets) + ctx partials (R2-proven)
        float ctxp[NB_];
        #pragma unroll
        for (int i = 0; i < NB_; ++i) {
            float c = 0.f;
            #pragma unroll
            for (int u = 0; u < 5; ++u) {
                const float wlo = wgt[i][u];
                const float whi = (u == 0) ? 0.f : wgt[i][u + 4];
                const float wv  = khalf ? whi : wlo;
                const int row = (baseA[i] + u + (khalf << 2) - K_) & (P_ - 1);
                c = fmaf(wv, ring[row * E_ + e], c);
            }
            c += __shfl_xor(c, 32);
            ctxp[i] = c;
        }

        float inp = bin_r;
        #pragma unroll
        for (int k = 0; k < 8; ++k) inp = fmaf(xt[k], win_r[k], inp);

        float xtn[8];
        if (t + 1 < T_) {
            float4 a0 = ((const float4*)(xb + (t + 1) * 8))[0];
            float4 a1 = ((const float4*)(xb + (t + 1) * 8))[1];
            xtn[0]=a0.x; xtn[1]=a0.y; xtn[2]=a0.z; xtn[3]=a0.w;
            xtn[4]=a1.x; xtn[5]=a1.y; xtn[6]=a1.z; xtn[7]=a1.w;
        } else {
            #pragma unroll
            for (int k = 0; k < 8; ++k) xtn[k] = 0.f;
        }

        float sv[NB_];

        if (!overlap) {
            // ================= FAST PATH: all 4 bots independent =================
            float s1v[NB_];
            #pragma unroll
            for (int j = 0; j < NB_; ++j)
                s1v[j] = fast_tanh(fmaf(sigc[j], ctxp[j], inp + pb_r[j] + hid[j]));
            if (lane < 32)
                s4[e] = make_float4(s1v[0], s1v[1], s1v[2], s1v[3]);
            __syncthreads();                      // ONE barrier for all 4 broadcasts

            // matvec: 64 ds_read_b128, each feeds 4 independent FMA chains
            float a0 = 0.f, a1 = 0.f, a2 = 0.f, a3 = 0.f;
            const float4* sp = s4 + khalf * 64;
            #pragma unroll
            for (int kk = 0; kk < 64; ++kk) {
                const float4 sb = sp[kk];
                const float w = wp[kk];
                a0 = fmaf(sb.x, w, a0);
                a1 = fmaf(sb.y, w, a1);
                a2 = fmaf(sb.z, w, a2);
                a3 = fmaf(sb.w, w, a3);
            }
            a0 += __shfl_xor(a0, 32);
            a1 += __shfl_xor(a1, 32);
            a2 += __shfl_xor(a2, 32);
            a3 += __shfl_xor(a3, 32);
            sv[0] = fast_tanh(a0 + bp_r);
            sv[1] = fast_tanh(a1 + bp_r);
            sv[2] = fast_tanh(a2 + bp_r);
            sv[3] = fast_tanh(a3 + bp_r);
            #pragma unroll
            for (int j = 0; j < NB_; ++j) hid[j] = sv[j];

            // 4 disjoint parity-owned scatters (plain +=, R2-proven)
            #pragma unroll
            for (int j = 0; j < NB_; ++j) {
                const int o0 = (baseA[j] ^ khalf) & 1;
                #pragma unroll
                for (int u = 0; u < 4; ++u) {
                    const float wv = o0 ? wgt[j][2 * u + 1] : wgt[j][2 * u];
                    const int r = (baseA[j] + 2 * u + o0 - K_) & (P_ - 1);
                    ring[r * E_ + e] += wv * sv[j];
                }
                if (o0 == 0) {
                    const int r = (baseA[j] + 8 - K_) & (P_ - 1);
                    ring[r * E_ + e] += wgt[j][8] * sv[j];
                }
            }
        } else {
            // ================= SLOW PATH: verbatim R2 serial chain ===============
            // cross-bot correction coefficients (only needed here)
            float coefm[NB_][NB_];
            #pragma unroll
            for (int j = 1; j < NB_; ++j) {
                #pragma unroll
                for (int i = 0; i < j; ++i) {
                    const int dd = ddm[j][i];
                    float c = 0.f;
                    if (dd >= -8 && dd <= 8) {
                        const float A = (float)dd - fA[i];
                        const float s  = __expf(-0.25f * (A - fA[j]));
                        const float G  = __expf(0.125f * (fA[i] * fA[i] - A * A));
                        const float s2p = s * s, s3p = s2p * s, s4p = s2p * s2p;
                        const float si = rcpf(s), si2 = si * si, si3 = si2 * si, si4 = si2 * si2;
                        float acc = 0.f;
                        acc += (dd >= 0)              ? Dw4 * si4 : 0.f;
                        acc += (dd >= -1 && dd <= 7)  ? Dw3 * si3 : 0.f;
                        acc += (dd >= -2 && dd <= 6)  ? Dw2 * si2 : 0.f;
                        acc += (dd >= -3 && dd <= 5)  ? Dw1 * si  : 0.f;
                        acc += (dd >= -4 && dd <= 4)  ? 1.0f      : 0.f;
                        acc += (dd >= -5 && dd <= 3)  ? Dw1 * s   : 0.f;
                        acc += (dd >= -6 && dd <= 2)  ? Dw2 * s2p : 0.f;
                        acc += (dd >= -7 && dd <= 1)  ? Dw3 * s3p : 0.f;
                        acc += (dd <= 0)              ? Dw4 * s4p : 0.f;
                        c = psinv[i] * psinv[j] * G * acc;
                    }
                    coefm[j][i] = c;
                }
            }

            #pragma unroll
            for (int j = 0; j < NB_; ++j) {
                float ctx = ctxp[j];
                #pragma unroll
                for (int i = 0; i < j; ++i) ctx = fmaf(coefm[j][i], sv[i], ctx);
                const float s1 = fast_tanh(fmaf(sigc[j], ctx, inp + pb_r[j] + hid[j]));
                if (lane < 32) s_buf[(j & 1) * E_ + e] = s1;
                __syncthreads();                  // s broadcast ready

                const float4* sp = (const float4*)(s_buf + (j & 1) * E_ + khalf * 64);
                float acc = 0.f;
                #pragma unroll
                for (int k4 = 0; k4 < 16; ++k4) {
                    const float4 sq = sp[k4];
                    acc = fmaf(sq.x, wp[4 * k4 + 0], acc);
                    acc = fmaf(sq.y, wp[4 * k4 + 1], acc);
                    acc = fmaf(sq.z, wp[4 * k4 + 2], acc);
                    acc = fmaf(sq.w, wp[4 * k4 + 3], acc);
                }
                acc += __shfl_xor(acc, 32);
                const float s2 = fast_tanh(acc + bp_r);
                sv[j] = s2; hid[j] = s2;

                const int o0 = (baseA[j] ^ khalf) & 1;
                #pragma unroll
                for (int u = 0; u < 4; ++u) {
                    const float wv = o0 ? wgt[j][2 * u + 1] : wgt[j][2 * u];
                    const int r = (baseA[j] + 2 * u + o0 - K_) & (P_ - 1);
                    ring[r * E_ + e] += wv * s2;
                }
                if (o0 == 0) {
                    const int r = (baseA[j] + 8 - K_) & (P_ - 1);
                    ring[r * E_ + e] += wgt[j][8] * s2;
                }
            }
        }

        // ---- jump dots (khalf0: bots 0,1; khalf1: bots 2,3)
        {
            float va = khalf ? sv[2] * jw_r[2] : sv[0] * jw_r[0];
            float vb = khalf ? sv[3] * jw_r[3] : sv[1] * jw_r[1];
            #pragma unroll
            for (int off = 1; off < 32; off <<= 1) {
                va += __shfl_xor(va, off);
                vb += __shfl_xor(vb, off);
            }
            if ((lane & 31) == 0)
                ((float2*)red)[wave * 2 + khalf] = make_float2(va, vb);
        }

        // ---- out dots (khalf0: dims 0-3; khalf1: dims 4-7)
        {
            const float ssum = (sv[0] + sv[1]) + (sv[2] + sv[3]);
            float u0 = ssum * wsel[0], u1 = ssum * wsel[1],
                  u2 = ssum * wsel[2], u3 = ssum * wsel[3];
            #pragma unroll
            for (int off = 1; off < 32; off <<= 1) {
                u0 += __shfl_xor(u0, off); u1 += __shfl_xor(u1, off);
                u2 += __shfl_xor(u2, off); u3 += __shfl_xor(u3, off);
            }
            if ((lane & 31) == 0)
                ((float4*)redo)[wave * 2 + khalf] = make_float4(u0, u1, u2, u3);
        }

        __syncthreads();                          // scatters + red/redo visible

        {
            const float4 r0 = ((const float4*)red)[0];
            const float4 r1 = ((const float4*)red)[1];
            const float4 r2 = ((const float4*)red)[2];
            const float4 r3 = ((const float4*)red)[3];
            const float zz[4] = {
                ((r0.x + r1.x) + (r2.x + r3.x)) + jb_r[0],
                ((r0.y + r1.y) + (r2.y + r3.y)) + jb_r[1],
                ((r0.z + r1.z) + (r2.z + r3.z)) + jb_r[2],
                ((r0.w + r1.w) + (r2.w + r3.w)) + jb_r[3]};
            #pragma unroll
            for (int i = 0; i < NB_; ++i) {
                float np;
                if (zz[i] > 0.0f) np = jt[i];
                else { np = ptrv[i] + 1.0f; if (np >= 256.0f) np -= 256.0f; }
                ptrv[i] = np;
            }
        }
        if (tid < 8) {
            const float ov = 0.25f * ((redo[tid] + redo[8 + tid]) +
                                      (redo[16 + tid] + redo[24 + tid])) + bout_r;
            out[((size_t)b * T_ + t) * 8 + tid] = ov;
        }

        #pragma unroll
        for (int k = 0; k < 8; ++k) xt[k] = xtn[k];
    }
}

extern "C" void kernel_launch(void* const* d_in, const int* in_sizes, int n_in,
                              void* d_out, int out_size, void* d_ws, size_t ws_size,
                              hipStream_t stream) {
    (void)in_sizes; (void)n_in; (void)out_size; (void)d_ws; (void)ws_size;
    swarm_ring_kernel<<<dim3(B_), dim3(256), 0, stream>>>(
        (const float*)d_in[0],  (const float*)d_in[1],  (const float*)d_in[2],
        (const float*)d_in[3],  (const float*)d_in[4],  (const float*)d_in[5],
        (const float*)d_in[6],  (const float*)d_in[7],  (const float*)d_in[8],
        (const float*)d_in[9],  (const float*)d_in[10], (const float*)d_in[11],
        (const float*)d_in[12], (float*)d_out);
}

// Round 8
// 2146.901 us; speedup vs baseline: 4.6374x; 1.0131x over previous
//
#include <hip/hip_runtime.h>
#include <cmath>

namespace {
constexpr int B_ = 16, T_ = 512, P_ = 256, E_ = 128, NB_ = 4, K_ = 4;

__device__ __forceinline__ float rcpf(float x) { return __builtin_amdgcn_rcpf(x); }
__device__ __forceinline__ float fast_tanh(float x) {
    float a = fabsf(x);
    float t = __expf(-2.0f * a);
    float r = 1.0f - 2.0f * t * rcpf(1.0f + t);
    return copysignf(r, x);
}
}

// R7-proven skeleton: 4 waves / 256 threads, 1 block per batch, ring in LDS,
// e = 32*wave + (lane&31), khalf = lane>>5, fast path when all bot windows
// disjoint (block-uniform test), verbatim R2 serial chain otherwise.
// R8: out-projection deferred 8 steps. Per step lanes<32 write ssum[e] into a
// 16-slot LDS history ring (stride 132, conflict-free); every 8th step wave 0
// computes the 64 (t,m) dots after the existing barrier and stores 64
// contiguous floats. Removes 20 shfl/wave/step from the shared DS pipe and
// the pre-barrier global store (vmcnt drain). Jump dots untouched ->
// trajectories bit-identical to R7.
__global__ __launch_bounds__(256, 1)
void swarm_ring_kernel(const float* __restrict__ x,            // (B,T,8)
                       const float* __restrict__ W_in,         // (8,E)
                       const float* __restrict__ b_in,         // (E)
                       const float* __restrict__ W_out,        // (E,8)
                       const float* __restrict__ b_out,        // (8)
                       const float* __restrict__ W_p,          // (E,E)
                       const float* __restrict__ b_p,          // (E)
                       const float* __restrict__ ptr_dest,     // (NB,P)
                       const float* __restrict__ jump_W,       // (NB,E)
                       const float* __restrict__ jump_b,       // (NB)
                       const float* __restrict__ ctx_strength, // (NB)
                       const float* __restrict__ phase_bias,   // (NB,E)
                       const float* __restrict__ pointer_init, // (NB,B)
                       float* __restrict__ out)                // (B,T,8)
{
    __shared__ alignas(16) float  ring[P_ * E_];    // 128 KiB
    __shared__ alignas(16) float  s_buf[2 * E_];    // slow path s broadcast
    __shared__ alignas(16) float4 s4[E_];           // fast path: s1 of bots 0..3
    __shared__ alignas(16) float  red[16];          // jump dots
    __shared__ alignas(16) float  hist[16][132];    // ssum history ring (pad 132)
    __shared__ alignas(16) float  wout_s[8][132];   // 0.25 * W_out^T, padded

    const int tid   = threadIdx.x;
    const int b     = blockIdx.x;
    const int wave  = tid >> 6;
    const int lane  = tid & 63;
    const int khalf = lane >> 5;
    const int e     = (wave << 5) | (lane & 31);

    for (int k4 = tid; k4 < P_ * E_ / 4; k4 += 256)
        ((float4*)ring)[k4] = make_float4(0.f, 0.f, 0.f, 0.f);
    for (int idx = tid; idx < 8 * E_; idx += 256) {       // stage 0.25*W_out^T
        const int m = idx >> 7, ee = idx & 127;
        wout_s[m][ee] = W_out[ee * 8 + m] * 0.25f;
    }

    float wp[64];                                   // W_p[khalf*64+kk][e]
    #pragma unroll
    for (int kk = 0; kk < 64; ++kk)
        wp[kk] = W_p[(khalf * 64 + kk) * E_ + e];

    const float bin_r = b_in[e];
    const float bp_r  = b_p[e];
    float win_r[8];
    #pragma unroll
    for (int k = 0; k < 8; ++k) win_r[k] = W_in[k * E_ + e];
    const float bout_m = b_out[tid & 7];            // for batch-reduce lanes

    float pb_r[NB_], jw_r[NB_], sigc[NB_], jb_r[NB_], hid[NB_], ptrv[NB_];
    #pragma unroll
    for (int i = 0; i < NB_; ++i) {
        pb_r[i] = 0.1f * phase_bias[i * E_ + e];
        jw_r[i] = jump_W[i * E_ + e];
        sigc[i] = 1.0f / (1.0f + __expf(-ctx_strength[i]));
        jb_r[i] = jump_b[i];
        hid[i]  = 0.0f;
        ptrv[i] = pointer_init[i * B_ + b];
    }

    const float* xb = x + (size_t)b * T_ * 8;
    float xt[8];
    {
        float4 a0 = ((const float4*)xb)[0], a1 = ((const float4*)xb)[1];
        xt[0]=a0.x; xt[1]=a0.y; xt[2]=a0.z; xt[3]=a0.w;
        xt[4]=a1.x; xt[5]=a1.y; xt[6]=a1.z; xt[7]=a1.w;
    }

    const float Cw1 = 0.8824969f, Cw2 = 0.60653066f, Cw3 = 0.32465247f, Cw4 = 0.13533528f;
    const float Dw1 = 0.7788008f, Dw2 = 0.36787944f, Dw3 = 0.105399225f, Dw4 = 0.018315639f;

    __syncthreads();

    for (int t = 0; t < T_; ++t) {
        // ---- geometry, softmax weights, jump-target prefetch (R2-proven)
        int   baseA[NB_];
        float fA[NB_], psinv[NB_], jt[NB_], wgt[NB_][9];
        #pragma unroll
        for (int i = 0; i < NB_; ++i) {
            const float p = ptrv[i];
            const int base = (int)p;
            baseA[i] = base;
            jt[i] = ptr_dest[i * P_ + base];
            const float f = p - (float)base;
            fA[i] = f;
            const float r  = __expf(0.25f * f);
            const float r2 = r * r, r3 = r2 * r, r4 = r2 * r2;
            const float ri = rcpf(r), ri2 = ri * ri, ri3 = ri2 * ri, ri4 = ri2 * ri2;
            const float p0 = Cw4*ri4, p1 = Cw3*ri3, p2 = Cw2*ri2, p3 = Cw1*ri, p4 = 1.0f,
                        p5 = Cw1*r,  p6 = Cw2*r2,  p7 = Cw3*r3,  p8 = Cw4*r4;
            const float sum = ((p0+p1)+(p2+p3)) + ((p4+p5)+(p6+p7)) + p8;
            const float inv = rcpf(sum);
            psinv[i] = inv;
            wgt[i][0]=p0*inv; wgt[i][1]=p1*inv; wgt[i][2]=p2*inv; wgt[i][3]=p3*inv;
            wgt[i][4]=p4*inv; wgt[i][5]=p5*inv; wgt[i][6]=p6*inv; wgt[i][7]=p7*inv;
            wgt[i][8]=p8*inv;
        }

        // ---- block-uniform independence test (pointers only)
        int ddm[NB_][NB_];
        bool overlap = false;
        #pragma unroll
        for (int j = 1; j < NB_; ++j)
            #pragma unroll
            for (int i = 0; i < j; ++i) {
                const int dd = ((baseA[j] - baseA[i] + 128) & 255) - 128;
                ddm[j][i] = dd;
                overlap = overlap || (dd >= -8 && dd <= 8);
            }

        // ---- gathers (khalf-split offsets) + ctx partials (R2-proven)
        float ctxp[NB_];
        #pragma unroll
        for (int i = 0; i < NB_; ++i) {
            float c = 0.f;
            #pragma unroll
            for (int u = 0; u < 5; ++u) {
                const float wlo = wgt[i][u];
                const float whi = (u == 0) ? 0.f : wgt[i][u + 4];
                const float wv  = khalf ? whi : wlo;
                const int row = (baseA[i] + u + (khalf << 2) - K_) & (P_ - 1);
                c = fmaf(wv, ring[row * E_ + e], c);
            }
            c += __shfl_xor(c, 32);
            ctxp[i] = c;
        }

        float inp = bin_r;
        #pragma unroll
        for (int k = 0; k < 8; ++k) inp = fmaf(xt[k], win_r[k], inp);

        float xtn[8];
        if (t + 1 < T_) {
            float4 a0 = ((const float4*)(xb + (t + 1) * 8))[0];
            float4 a1 = ((const float4*)(xb + (t + 1) * 8))[1];
            xtn[0]=a0.x; xtn[1]=a0.y; xtn[2]=a0.z; xtn[3]=a0.w;
            xtn[4]=a1.x; xtn[5]=a1.y; xtn[6]=a1.z; xtn[7]=a1.w;
        } else {
            #pragma unroll
            for (int k = 0; k < 8; ++k) xtn[k] = 0.f;
        }

        float sv[NB_];

        if (!overlap) {
            // ================= FAST PATH: all 4 bots independent =================
            float s1v[NB_];
            #pragma unroll
            for (int j = 0; j < NB_; ++j)
                s1v[j] = fast_tanh(fmaf(sigc[j], ctxp[j], inp + pb_r[j] + hid[j]));
            if (lane < 32)
                s4[e] = make_float4(s1v[0], s1v[1], s1v[2], s1v[3]);
            __syncthreads();                      // ONE barrier for all 4 broadcasts

            float a0 = 0.f, a1 = 0.f, a2 = 0.f, a3 = 0.f;
            const float4* sp = s4 + khalf * 64;
            #pragma unroll
            for (int kk = 0; kk < 64; ++kk) {
                const float4 sb = sp[kk];
                const float w = wp[kk];
                a0 = fmaf(sb.x, w, a0);
                a1 = fmaf(sb.y, w, a1);
                a2 = fmaf(sb.z, w, a2);
                a3 = fmaf(sb.w, w, a3);
            }
            a0 += __shfl_xor(a0, 32);
            a1 += __shfl_xor(a1, 32);
            a2 += __shfl_xor(a2, 32);
            a3 += __shfl_xor(a3, 32);
            sv[0] = fast_tanh(a0 + bp_r);
            sv[1] = fast_tanh(a1 + bp_r);
            sv[2] = fast_tanh(a2 + bp_r);
            sv[3] = fast_tanh(a3 + bp_r);
            #pragma unroll
            for (int j = 0; j < NB_; ++j) hid[j] = sv[j];

            #pragma unroll
            for (int j = 0; j < NB_; ++j) {
                const int o0 = (baseA[j] ^ khalf) & 1;
                #pragma unroll
                for (int u = 0; u < 4; ++u) {
                    const float wv = o0 ? wgt[j][2 * u + 1] : wgt[j][2 * u];
                    const int r = (baseA[j] + 2 * u + o0 - K_) & (P_ - 1);
                    ring[r * E_ + e] += wv * sv[j];
                }
                if (o0 == 0) {
                    const int r = (baseA[j] + 8 - K_) & (P_ - 1);
                    ring[r * E_ + e] += wgt[j][8] * sv[j];
                }
            }
        } else {
            // ================= SLOW PATH: verbatim R2 serial chain ===============
            float coefm[NB_][NB_];
            #pragma unroll
            for (int j = 1; j < NB_; ++j) {
                #pragma unroll
                for (int i = 0; i < j; ++i) {
                    const int dd = ddm[j][i];
                    float c = 0.f;
                    if (dd >= -8 && dd <= 8) {
                        const float A = (float)dd - fA[i];
                        const float s  = __expf(-0.25f * (A - fA[j]));
                        const float G  = __expf(0.125f * (fA[i] * fA[i] - A * A));
                        const float s2p = s * s, s3p = s2p * s, s4p = s2p * s2p;
                        const float si = rcpf(s), si2 = si * si, si3 = si2 * si, si4 = si2 * si2;
                        float acc = 0.f;
                        acc += (dd >= 0)              ? Dw4 * si4 : 0.f;
                        acc += (dd >= -1 && dd <= 7)  ? Dw3 * si3 : 0.f;
                        acc += (dd >= -2 && dd <= 6)  ? Dw2 * si2 : 0.f;
                        acc += (dd >= -3 && dd <= 5)  ? Dw1 * si  : 0.f;
                        acc += (dd >= -4 && dd <= 4)  ? 1.0f      : 0.f;
                        acc += (dd >= -5 && dd <= 3)  ? Dw1 * s   : 0.f;
                        acc += (dd >= -6 && dd <= 2)  ? Dw2 * s2p : 0.f;
                        acc += (dd >= -7 && dd <= 1)  ? Dw3 * s3p : 0.f;
                        acc += (dd <= 0)              ? Dw4 * s4p : 0.f;
                        c = psinv[i] * psinv[j] * G * acc;
                    }
                    coefm[j][i] = c;
                }
            }

            #pragma unroll
            for (int j = 0; j < NB_; ++j) {
                float ctx = ctxp[j];
                #pragma unroll
                for (int i = 0; i < j; ++i) ctx = fmaf(coefm[j][i], sv[i], ctx);
                const float s1 = fast_tanh(fmaf(sigc[j], ctx, inp + pb_r[j] + hid[j]));
                if (lane < 32) s_buf[(j & 1) * E_ + e] = s1;
                __syncthreads();                  // s broadcast ready

                const float4* sp = (const float4*)(s_buf + (j & 1) * E_ + khalf * 64);
                float acc = 0.f;
                #pragma unroll
                for (int k4 = 0; k4 < 16; ++k4) {
                    const float4 sq = sp[k4];
                    acc = fmaf(sq.x, wp[4 * k4 + 0], acc);
                    acc = fmaf(sq.y, wp[4 * k4 + 1], acc);
                    acc = fmaf(sq.z, wp[4 * k4 + 2], acc);
                    acc = fmaf(sq.w, wp[4 * k4 + 3], acc);
                }
                acc += __shfl_xor(acc, 32);
                const float s2 = fast_tanh(acc + bp_r);
                sv[j] = s2; hid[j] = s2;

                const int o0 = (baseA[j] ^ khalf) & 1;
                #pragma unroll
                for (int u = 0; u < 4; ++u) {
                    const float wv = o0 ? wgt[j][2 * u + 1] : wgt[j][2 * u];
                    const int r = (baseA[j] + 2 * u + o0 - K_) & (P_ - 1);
                    ring[r * E_ + e] += wv * s2;
                }
                if (o0 == 0) {
                    const int r = (baseA[j] + 8 - K_) & (P_ - 1);
                    ring[r * E_ + e] += wgt[j][8] * s2;
                }
            }
        }

        // ---- jump dots (khalf0: bots 0,1; khalf1: bots 2,3) -- unchanged
        {
            float va = khalf ? sv[2] * jw_r[2] : sv[0] * jw_r[0];
            float vb = khalf ? sv[3] * jw_r[3] : sv[1] * jw_r[1];
            #pragma unroll
            for (int off = 1; off < 32; off <<= 1) {
                va += __shfl_xor(va, off);
                vb += __shfl_xor(vb, off);
            }
            if ((lane & 31) == 0)
                ((float2*)red)[wave * 2 + khalf] = make_float2(va, vb);
        }

        // ---- ssum -> history ring (replaces per-step out-dot shuffles)
        {
            const float ssum = (sv[0] + sv[1]) + (sv[2] + sv[3]);
            if (lane < 32) hist[t & 15][e] = ssum;
        }

        __syncthreads();                          // scatters + red + hist visible

        {
            const float4 r0 = ((const float4*)red)[0];
            const float4 r1 = ((const float4*)red)[1];
            const float4 r2 = ((const float4*)red)[2];
            const float4 r3 = ((const float4*)red)[3];
            const float zz[4] = {
                ((r0.x + r1.x) + (r2.x + r3.x)) + jb_r[0],
                ((r0.y + r1.y) + (r2.y + r3.y)) + jb_r[1],
                ((r0.z + r1.z) + (r2.z + r3.z)) + jb_r[2],
                ((r0.w + r1.w) + (r2.w + r3.w)) + jb_r[3]};
            #pragma unroll
            for (int i = 0; i < NB_; ++i) {
                float np;
                if (zz[i] > 0.0f) np = jt[i];
                else { np = ptrv[i] + 1.0f; if (np >= 256.0f) np -= 256.0f; }
                ptrv[i] = np;
            }
        }

        // ---- every 8th step: wave 0 computes 64 (t,m) out dots and stores.
        // Reads hist slots (t-7..t)&15 while other waves write slot (t+1)&15
        // of the 16-ring -> no race. Uses existing barriers only.
        if ((t & 7) == 7 && tid < 64) {
            const int tt = tid >> 3;              // 0..7 (timestep in batch)
            const int m  = tid & 7;               // output dim
            const float* hrow = hist[(t - 7 + tt) & 15];
            const float* wrow = wout_s[m];
            float acc = 0.f;
            #pragma unroll
            for (int q = 0; q < 32; ++q) {
                const float4 h4 = ((const float4*)hrow)[q];
                const float4 w4 = ((const float4*)wrow)[q];
                acc += ((h4.x * w4.x + h4.y * w4.y) + (h4.z * w4.z + h4.w * w4.w));
            }
            out[((size_t)b * T_ + (t - 7 + tt)) * 8 + m] = acc + bout_m;
        }

        #pragma unroll
        for (int k = 0; k < 8; ++k) xt[k] = xtn[k];
    }
}

extern "C" void kernel_launch(void* const* d_in, const int* in_sizes, int n_in,
                              void* d_out, int out_size, void* d_ws, size_t ws_size,
                              hipStream_t stream) {
    (void)in_sizes; (void)n_in; (void)out_size; (void)d_ws; (void)ws_size;
    swarm_ring_kernel<<<dim3(B_), dim3(256), 0, stream>>>(
        (const float*)d_in[0],  (const float*)d_in[1],  (const float*)d_in[2],
        (const float*)d_in[3],  (const float*)d_in[4],  (const float*)d_in[5],
        (const float*)d_in[6],  (const float*)d_in[7],  (const float*)d_in[8],
        (const float*)d_in[9],  (const float*)d_in[10], (const float*)d_in[11],
        (const float*)d_in[12], (float*)d_out);
}

// Round 9
// 2058.351 us; speedup vs baseline: 4.8370x; 1.0430x over previous
//
#include <hip/hip_runtime.h>
#include <cmath>

namespace {
constexpr int B_ = 16, T_ = 512, P_ = 256, E_ = 128, NB_ = 4, K_ = 4;

__device__ __forceinline__ float rcpf(float x) { return __builtin_amdgcn_rcpf(x); }
__device__ __forceinline__ float fast_tanh(float x) {
    float a = fabsf(x);
    float t = __expf(-2.0f * a);
    float r = 1.0f - 2.0f * t * rcpf(1.0f + t);
    return copysignf(r, x);
}
// sum over the 4 kq groups (lanes l, l^16, l^32, l^48)
__device__ __forceinline__ float redkq(float v) {
    v += __shfl_xor(v, 16);
    v += __shfl_xor(v, 32);
    return v;
}
// select a[kq] with compile-time indexing only (no scratch demotion)
__device__ __forceinline__ float sel4(int kq, float a, float b, float c, float d) {
    const float t0 = (kq & 1) ? b : a;
    const float t1 = (kq & 1) ? d : c;
    return (kq & 2) ? t1 : t0;
}
}

// R7/R8-proven skeleton (fast/slow split, plain __syncthreads, plain +=
// scatter, hist-deferred out). R9: e-PAIR data layout. Lane (w,l):
//   pair p = 16*w + (l&15)  -> owns e0=2p, e0+1 ;  kq = l>>4 (4-way k-split)
// Gather/scatter are b64 (2 e per access), matvec reads s4 128x b128 total
// (each read amortized over 2 outputs), combines via 2 shfl_xor levels.
// W_p slice stays 64 floats/lane.
__global__ __launch_bounds__(256, 1)
void swarm_ring_kernel(const float* __restrict__ x,            // (B,T,8)
                       const float* __restrict__ W_in,         // (8,E)
                       const float* __restrict__ b_in,         // (E)
                       const float* __restrict__ W_out,        // (E,8)
                       const float* __restrict__ b_out,        // (8)
                       const float* __restrict__ W_p,          // (E,E)
                       const float* __restrict__ b_p,          // (E)
                       const float* __restrict__ ptr_dest,     // (NB,P)
                       const float* __restrict__ jump_W,       // (NB,E)
                       const float* __restrict__ jump_b,       // (NB)
                       const float* __restrict__ ctx_strength, // (NB)
                       const float* __restrict__ phase_bias,   // (NB,E)
                       const float* __restrict__ pointer_init, // (NB,B)
                       float* __restrict__ out)                // (B,T,8)
{
    __shared__ alignas(16) float  ring[P_ * E_];    // 128 KiB
    __shared__ alignas(16) float4 s4[E_];           // fast: s1 of bots 0..3 per k
    __shared__ alignas(16) float  sbuf[2 * E_];     // slow: flat s broadcast
    __shared__ alignas(16) float  red[16];          // per-wave jump partials (float4)
    __shared__ alignas(16) float  hist[16][132];    // ssum history ring
    __shared__ alignas(16) float  wout_s[8][132];   // 0.25 * W_out^T

    const int tid = threadIdx.x;
    const int b   = blockIdx.x;
    const int w   = tid >> 6;
    const int l   = tid & 63;
    const int sub = l & 15;
    const int kq  = l >> 4;                         // 0..3
    const int e0  = ((w << 4) | sub) << 1;          // owned e-pair: e0, e0+1

    for (int k4 = tid; k4 < P_ * E_ / 4; k4 += 256)
        ((float4*)ring)[k4] = make_float4(0.f, 0.f, 0.f, 0.f);
    for (int idx = tid; idx < 8 * E_; idx += 256) {
        const int m = idx >> 7, ee = idx & 127;
        wout_s[m][ee] = W_out[ee * 8 + m] * 0.25f;
    }

    float2 wp2[32];                                 // W_p[32*kq+kk][e0..e0+1]
    #pragma unroll
    for (int kk = 0; kk < 32; ++kk)
        wp2[kk] = *(const float2*)(W_p + (kq * 32 + kk) * E_ + e0);

    const float2 bin2 = *(const float2*)(b_in + e0);
    const float2 bp2  = *(const float2*)(b_p + e0);
    const float  bout_m = b_out[tid & 7];

    float2 pb2[NB_], jw2[NB_], hid2[NB_];
    float  sigc[NB_], jb_r[NB_], ptrv[NB_];
    #pragma unroll
    for (int i = 0; i < NB_; ++i) {
        const float2 pb = *(const float2*)(phase_bias + i * E_ + e0);
        pb2[i] = make_float2(0.1f * pb.x, 0.1f * pb.y);
        jw2[i] = *(const float2*)(jump_W + i * E_ + e0);
        sigc[i] = 1.0f / (1.0f + __expf(-ctx_strength[i]));
        jb_r[i] = jump_b[i];
        hid2[i] = make_float2(0.f, 0.f);
        ptrv[i] = pointer_init[i * B_ + b];
    }

    const float* xb = x + (size_t)b * T_ * 8;
    float xt[8];
    {
        float4 a0 = ((const float4*)xb)[0], a1 = ((const float4*)xb)[1];
        xt[0]=a0.x; xt[1]=a0.y; xt[2]=a0.z; xt[3]=a0.w;
        xt[4]=a1.x; xt[5]=a1.y; xt[6]=a1.z; xt[7]=a1.w;
    }

    const float Cw1 = 0.8824969f, Cw2 = 0.60653066f, Cw3 = 0.32465247f, Cw4 = 0.13533528f;
    const float Dw1 = 0.7788008f, Dw2 = 0.36787944f, Dw3 = 0.105399225f, Dw4 = 0.018315639f;

    __syncthreads();

    for (int t = 0; t < T_; ++t) {
        // ---- geometry, softmax weights, jump-target prefetch (proven math)
        int   baseA[NB_];
        float fA[NB_], psinv[NB_], jt[NB_], wgt[NB_][9];
        #pragma unroll
        for (int i = 0; i < NB_; ++i) {
            const float p = ptrv[i];
            const int base = (int)p;
            baseA[i] = base;
            jt[i] = ptr_dest[i * P_ + base];
            const float f = p - (float)base;
            fA[i] = f;
            const float r  = __expf(0.25f * f);
            const float r2 = r * r, r3 = r2 * r, r4 = r2 * r2;
            const float ri = rcpf(r), ri2 = ri * ri, ri3 = ri2 * ri, ri4 = ri2 * ri2;
            const float p0 = Cw4*ri4, p1 = Cw3*ri3, p2 = Cw2*ri2, p3 = Cw1*ri, p4 = 1.0f,
                        p5 = Cw1*r,  p6 = Cw2*r2,  p7 = Cw3*r3,  p8 = Cw4*r4;
            const float sum = ((p0+p1)+(p2+p3)) + ((p4+p5)+(p6+p7)) + p8;
            const float inv = rcpf(sum);
            psinv[i] = inv;
            wgt[i][0]=p0*inv; wgt[i][1]=p1*inv; wgt[i][2]=p2*inv; wgt[i][3]=p3*inv;
            wgt[i][4]=p4*inv; wgt[i][5]=p5*inv; wgt[i][6]=p6*inv; wgt[i][7]=p7*inv;
            wgt[i][8]=p8*inv;
        }

        // ---- block-uniform independence test
        int ddm[NB_][NB_];
        bool overlap = false;
        #pragma unroll
        for (int j = 1; j < NB_; ++j)
            #pragma unroll
            for (int i = 0; i < j; ++i) {
                const int dd = ((baseA[j] - baseA[i] + 128) & 255) - 128;
                ddm[j][i] = dd;
                overlap = overlap || (dd >= -8 && dd <= 8);
            }

        // ---- gathers: rows kq, kq+4 (+8 on kq0), b64; combine across kq
        float  ws0[NB_], ws1[NB_];                  // selected weights (reused by scatter)
        float2 ctxp2[NB_];
        #pragma unroll
        for (int i = 0; i < NB_; ++i) {
            ws0[i] = sel4(kq, wgt[i][0], wgt[i][1], wgt[i][2], wgt[i][3]);
            ws1[i] = sel4(kq, wgt[i][4], wgt[i][5], wgt[i][6], wgt[i][7]);
            const int r0 = (baseA[i] + kq - K_) & (P_ - 1);
            const int r1 = (baseA[i] + kq + 4 - K_) & (P_ - 1);
            const float2 g0 = *(const float2*)(ring + r0 * E_ + e0);
            const float2 g1 = *(const float2*)(ring + r1 * E_ + e0);
            float cx = fmaf(ws1[i], g1.x, ws0[i] * g0.x);
            float cy = fmaf(ws1[i], g1.y, ws0[i] * g0.y);
            if (kq == 0) {
                const int r2 = (baseA[i] + 8 - K_) & (P_ - 1);
                const float2 g2 = *(const float2*)(ring + r2 * E_ + e0);
                cx = fmaf(wgt[i][8], g2.x, cx);
                cy = fmaf(wgt[i][8], g2.y, cy);
            }
            ctxp2[i] = make_float2(redkq(cx), redkq(cy));
        }

        // ---- inp = x_t @ W_in + b_in (W_in per-step loads, L1/L2-hot)
        float2 inp2 = bin2;
        #pragma unroll
        for (int k = 0; k < 8; ++k) {
            const float2 wk = *(const float2*)(W_in + k * E_ + e0);
            inp2.x = fmaf(xt[k], wk.x, inp2.x);
            inp2.y = fmaf(xt[k], wk.y, inp2.y);
        }

        float xtn[8];
        if (t + 1 < T_) {
            float4 a0 = ((const float4*)(xb + (t + 1) * 8))[0];
            float4 a1 = ((const float4*)(xb + (t + 1) * 8))[1];
            xtn[0]=a0.x; xtn[1]=a0.y; xtn[2]=a0.z; xtn[3]=a0.w;
            xtn[4]=a1.x; xtn[5]=a1.y; xtn[6]=a1.z; xtn[7]=a1.w;
        } else {
            #pragma unroll
            for (int k = 0; k < 8; ++k) xtn[k] = 0.f;
        }

        float2 sv2[NB_];

        if (!overlap) {
            // ================= FAST PATH: all 4 bots independent =================
            float2 s1v[NB_];
            #pragma unroll
            for (int j = 0; j < NB_; ++j) {
                s1v[j].x = fast_tanh(fmaf(sigc[j], ctxp2[j].x, inp2.x + pb2[j].x + hid2[j].x));
                s1v[j].y = fast_tanh(fmaf(sigc[j], ctxp2[j].y, inp2.y + pb2[j].y + hid2[j].y));
            }
            if (kq == 0) {
                s4[e0]     = make_float4(s1v[0].x, s1v[1].x, s1v[2].x, s1v[3].x);
                s4[e0 + 1] = make_float4(s1v[0].y, s1v[1].y, s1v[2].y, s1v[3].y);
            }
            __syncthreads();                        // ONE barrier for all 4 broadcasts

            float2 ab0 = make_float2(0.f, 0.f), ab1 = ab0, ab2 = ab0, ab3 = ab0;
            const float4* sp = s4 + kq * 32;
            #pragma unroll
            for (int kk = 0; kk < 32; ++kk) {
                const float4 sq = sp[kk];
                const float2 w2 = wp2[kk];
                ab0.x = fmaf(sq.x, w2.x, ab0.x); ab0.y = fmaf(sq.x, w2.y, ab0.y);
                ab1.x = fmaf(sq.y, w2.x, ab1.x); ab1.y = fmaf(sq.y, w2.y, ab1.y);
                ab2.x = fmaf(sq.z, w2.x, ab2.x); ab2.y = fmaf(sq.z, w2.y, ab2.y);
                ab3.x = fmaf(sq.w, w2.x, ab3.x); ab3.y = fmaf(sq.w, w2.y, ab3.y);
            }
            sv2[0] = make_float2(fast_tanh(redkq(ab0.x) + bp2.x), fast_tanh(redkq(ab0.y) + bp2.y));
            sv2[1] = make_float2(fast_tanh(redkq(ab1.x) + bp2.x), fast_tanh(redkq(ab1.y) + bp2.y));
            sv2[2] = make_float2(fast_tanh(redkq(ab2.x) + bp2.x), fast_tanh(redkq(ab2.y) + bp2.y));
            sv2[3] = make_float2(fast_tanh(redkq(ab3.x) + bp2.x), fast_tanh(redkq(ab3.y) + bp2.y));
            #pragma unroll
            for (int j = 0; j < NB_; ++j) hid2[j] = sv2[j];

            // disjoint b64 scatters: lane owns rows kq, kq+4 (+8 on kq0)
            #pragma unroll
            for (int j = 0; j < NB_; ++j) {
                const float2 s = sv2[j];
                const int r0 = (baseA[j] + kq - K_) & (P_ - 1);
                float2* q0 = (float2*)(ring + r0 * E_ + e0);
                float2 v0 = *q0;
                v0.x = fmaf(ws0[j], s.x, v0.x); v0.y = fmaf(ws0[j], s.y, v0.y);
                *q0 = v0;
                const int r1 = (baseA[j] + kq + 4 - K_) & (P_ - 1);
                float2* q1 = (float2*)(ring + r1 * E_ + e0);
                float2 v1 = *q1;
                v1.x = fmaf(ws1[j], s.x, v1.x); v1.y = fmaf(ws1[j], s.y, v1.y);
                *q1 = v1;
                if (kq == 0) {
                    const int r2 = (baseA[j] + 8 - K_) & (P_ - 1);
                    float2* q2 = (float2*)(ring + r2 * E_ + e0);
                    float2 v2 = *q2;
                    v2.x = fmaf(wgt[j][8], s.x, v2.x); v2.y = fmaf(wgt[j][8], s.y, v2.y);
                    *q2 = v2;
                }
            }
        } else {
            // ================= SLOW PATH: serial chain with coef corrections =====
            float coefm[NB_][NB_];
            #pragma unroll
            for (int j = 1; j < NB_; ++j) {
                #pragma unroll
                for (int i = 0; i < j; ++i) {
                    const int dd = ddm[j][i];
                    float c = 0.f;
                    if (dd >= -8 && dd <= 8) {
                        const float A = (float)dd - fA[i];
                        const float s  = __expf(-0.25f * (A - fA[j]));
                        const float G  = __expf(0.125f * (fA[i] * fA[i] - A * A));
                        const float s2p = s * s, s3p = s2p * s, s4p = s2p * s2p;
                        const float si = rcpf(s), si2 = si * si, si3 = si2 * si, si4 = si2 * si2;
                        float acc = 0.f;
                        acc += (dd >= 0)              ? Dw4 * si4 : 0.f;
                        acc += (dd >= -1 && dd <= 7)  ? Dw3 * si3 : 0.f;
                        acc += (dd >= -2 && dd <= 6)  ? Dw2 * si2 : 0.f;
                        acc += (dd >= -3 && dd <= 5)  ? Dw1 * si  : 0.f;
                        acc += (dd >= -4 && dd <= 4)  ? 1.0f      : 0.f;
                        acc += (dd >= -5 && dd <= 3)  ? Dw1 * s   : 0.f;
                        acc += (dd >= -6 && dd <= 2)  ? Dw2 * s2p : 0.f;
                        acc += (dd >= -7 && dd <= 1)  ? Dw3 * s3p : 0.f;
                        acc += (dd <= 0)              ? Dw4 * s4p : 0.f;
                        c = psinv[i] * psinv[j] * G * acc;
                    }
                    coefm[j][i] = c;
                }
            }

            #pragma unroll
            for (int j = 0; j < NB_; ++j) {
                float2 ctx = ctxp2[j];
                #pragma unroll
                for (int i = 0; i < j; ++i) {
                    ctx.x = fmaf(coefm[j][i], sv2[i].x, ctx.x);
                    ctx.y = fmaf(coefm[j][i], sv2[i].y, ctx.y);
                }
                float2 s1;
                s1.x = fast_tanh(fmaf(sigc[j], ctx.x, inp2.x + pb2[j].x + hid2[j].x));
                s1.y = fast_tanh(fmaf(sigc[j], ctx.y, inp2.y + pb2[j].y + hid2[j].y));
                if (kq == 0) *(float2*)(sbuf + (j & 1) * E_ + e0) = s1;
                __syncthreads();                    // s broadcast ready

                const float4* sp = (const float4*)(sbuf + (j & 1) * E_) + kq * 8;
                float ax = 0.f, ay = 0.f;
                #pragma unroll
                for (int kk = 0; kk < 8; ++kk) {
                    const float4 sq = sp[kk];
                    const float2 wa = wp2[4 * kk + 0], wb = wp2[4 * kk + 1];
                    const float2 wc = wp2[4 * kk + 2], wd = wp2[4 * kk + 3];
                    ax = fmaf(sq.x, wa.x, ax); ay = fmaf(sq.x, wa.y, ay);
                    ax = fmaf(sq.y, wb.x, ax); ay = fmaf(sq.y, wb.y, ay);
                    ax = fmaf(sq.z, wc.x, ax); ay = fmaf(sq.z, wc.y, ay);
                    ax = fmaf(sq.w, wd.x, ax); ay = fmaf(sq.w, wd.y, ay);
                }
                float2 s2;
                s2.x = fast_tanh(redkq(ax) + bp2.x);
                s2.y = fast_tanh(redkq(ay) + bp2.y);
                sv2[j] = s2; hid2[j] = s2;

                const int r0 = (baseA[j] + kq - K_) & (P_ - 1);
                float2* q0 = (float2*)(ring + r0 * E_ + e0);
                float2 v0 = *q0;
                v0.x = fmaf(ws0[j], s2.x, v0.x); v0.y = fmaf(ws0[j], s2.y, v0.y);
                *q0 = v0;
                const int r1 = (baseA[j] + kq + 4 - K_) & (P_ - 1);
                float2* q1 = (float2*)(ring + r1 * E_ + e0);
                float2 v1 = *q1;
                v1.x = fmaf(ws1[j], s2.x, v1.x); v1.y = fmaf(ws1[j], s2.y, v1.y);
                *q1 = v1;
                if (kq == 0) {
                    const int r2 = (baseA[j] + 8 - K_) & (P_ - 1);
                    float2* q2 = (float2*)(ring + r2 * E_ + e0);
                    float2 v2 = *q2;
                    v2.x = fmaf(wgt[j][8], s2.x, v2.x); v2.y = fmaf(wgt[j][8], s2.y, v2.y);
                    *q2 = v2;
                }
            }
        }

        // ---- jump dots: per-lane pair dot, reduce over the wave's 16 pairs
        {
            float vj0 = fmaf(sv2[0].y, jw2[0].y, sv2[0].x * jw2[0].x);
            float vj1 = fmaf(sv2[1].y, jw2[1].y, sv2[1].x * jw2[1].x);
            float vj2 = fmaf(sv2[2].y, jw2[2].y, sv2[2].x * jw2[2].x);
            float vj3 = fmaf(sv2[3].y, jw2[3].y, sv2[3].x * jw2[3].x);
            #pragma unroll
            for (int off = 1; off < 16; off <<= 1) {
                vj0 += __shfl_xor(vj0, off);
                vj1 += __shfl_xor(vj1, off);
                vj2 += __shfl_xor(vj2, off);
                vj3 += __shfl_xor(vj3, off);
            }
            if (l == 0)
                ((float4*)red)[w] = make_float4(vj0, vj1, vj2, vj3);
        }

        // ---- ssum -> history ring (kq0 lanes, b64)
        {
            float2 ssum2;
            ssum2.x = (sv2[0].x + sv2[1].x) + (sv2[2].x + sv2[3].x);
            ssum2.y = (sv2[0].y + sv2[1].y) + (sv2[2].y + sv2[3].y);
            if (kq == 0) *(float2*)(&hist[t & 15][e0]) = ssum2;
        }

        __syncthreads();                            // scatters + red + hist visible

        {
            const float4 r0 = ((const float4*)red)[0];
            const float4 r1 = ((const float4*)red)[1];
            const float4 r2 = ((const float4*)red)[2];
            const float4 r3 = ((const float4*)red)[3];
            const float zz[4] = {
                ((r0.x + r1.x) + (r2.x + r3.x)) + jb_r[0],
                ((r0.y + r1.y) + (r2.y + r3.y)) + jb_r[1],
                ((r0.z + r1.z) + (r2.z + r3.z)) + jb_r[2],
                ((r0.w + r1.w) + (r2.w + r3.w)) + jb_r[3]};
            #pragma unroll
            for (int i = 0; i < NB_; ++i) {
                float np;
                if (zz[i] > 0.0f) np = jt[i];
                else { np = ptrv[i] + 1.0f; if (np >= 256.0f) np -= 256.0f; }
                ptrv[i] = np;
            }
        }

        // ---- every 8th step: 64 threads compute the deferred out dots (R8-proven)
        if ((t & 7) == 7 && tid < 64) {
            const int tt = tid >> 3;
            const int m  = tid & 7;
            const float* hrow = hist[(t - 7 + tt) & 15];
            const float* wrow = wout_s[m];
            float acc = 0.f;
            #pragma unroll
            for (int q = 0; q < 32; ++q) {
                const float4 h4 = ((const float4*)hrow)[q];
                const float4 w4 = ((const float4*)wrow)[q];
                acc += ((h4.x * w4.x + h4.y * w4.y) + (h4.z * w4.z + h4.w * w4.w));
            }
            out[((size_t)b * T_ + (t - 7 + tt)) * 8 + m] = acc + bout_m;
        }

        #pragma unroll
        for (int k = 0; k < 8; ++k) xt[k] = xtn[k];
    }
}

extern "C" void kernel_launch(void* const* d_in, const int* in_sizes, int n_in,
                              void* d_out, int out_size, void* d_ws, size_t ws_size,
                              hipStream_t stream) {
    (void)in_sizes; (void)n_in; (void)out_size; (void)d_ws; (void)ws_size;
    swarm_ring_kernel<<<dim3(B_), dim3(256), 0, stream>>>(
        (const float*)d_in[0],  (const float*)d_in[1],  (const float*)d_in[2],
        (const float*)d_in[3],  (const float*)d_in[4],  (const float*)d_in[5],
        (const float*)d_in[6],  (const float*)d_in[7],  (const float*)d_in[8],
        (const float*)d_in[9],  (const float*)d_in[10], (const float*)d_in[11],
        (const float*)d_in[12], (float*)d_out);
}